// Round 8
// baseline (490.427 us; speedup 1.0000x reference)
//
#include <hip/hip_runtime.h>

typedef unsigned short ushort_t;
typedef short bf16x8 __attribute__((ext_vector_type(8)));
typedef float floatx4 __attribute__((ext_vector_type(4)));

// ---------- bf16 helpers (bit-level, RNE) ----------
__device__ __forceinline__ float bf2f(ushort_t u) {
    return __uint_as_float(((unsigned)u) << 16);
}
__device__ __forceinline__ ushort_t f2bf(float f) {
    unsigned u = __float_as_uint(f);
    unsigned rnd = 0x7fffu + ((u >> 16) & 1u);
    return (ushort_t)((u + rnd) >> 16);
}

// async global->LDS, 16B per lane; LDS dest = wave-uniform base + lane*16.
__device__ __forceinline__ void gload_lds16(const void* g, void* l) {
    __builtin_amdgcn_global_load_lds(
        (const __attribute__((address_space(1))) unsigned int*)g,
        (__attribute__((address_space(3))) unsigned int*)l,
        16, 0, 0);
}

// ---------- fp32 -> bf16 batch convert ----------
struct CvtArgs {
    const float* src[12];
    ushort_t* dst[12];
    int n4[12];
};

__global__ __launch_bounds__(256) void cvt_kernel(CvtArgs a) {
    int t = blockIdx.y;
    int n4 = a.n4[t];
    const float4* s = (const float4*)a.src[t];
    ushort_t* d = a.dst[t];
    int stride = gridDim.x * blockDim.x;
    for (int i = blockIdx.x * blockDim.x + threadIdx.x; i < n4; i += stride) {
        float4 v = s[i];
        ushort4 o;
        o.x = f2bf(v.x); o.y = f2bf(v.y); o.z = f2bf(v.z); o.w = f2bf(v.w);
        ((ushort4*)d)[i] = o;
    }
}

// ============================================================================
// Shared GEMM pieces. Per-dispatch schedule choice is EMPIRICAL (r5 vs r7
// measured): 4-phase full-acc wins for K=1024/ldk=1024 (proj, score);
// 8-phase wins for the split-K PV (K=2048, ldk=4096): 93.7 vs 111.5 us.
// Both use: 256x256 tile, 8 waves (2Mx4N), chunk-linear LDS slots
// (chunk c = i*64+q*16+r holds X[i*16+r][q*8..+7]; staging dest and
// fragment ds_reads lane-linear, 0 bank conflicts), gload_lds16 staging,
// counted vmcnt (never 0 in steady state), raw s_barrier, setprio around
// MFMA clusters, XCD 2D-rect swizzle, split-K (koff/ldk).
// ============================================================================
template<int NB> struct GemmArgs {
    const ushort_t* A[NB];
    const ushort_t* B[NB];
    const float* bias[NB];
    void* C[NB];
    int trans[NB];
    int koff[NB];
};

__device__ __forceinline__ void xcd_swz(int& tx, int& ty) {
    const int gx = gridDim.x, gy = gridDim.y;
    const int l = blockIdx.x + blockIdx.y * gx;
    const int xcd = l & 7, s = l >> 3;
    const int rw = gx >> 2;        // rect width  (4 x-groups)
    const int rh = gy >> 1;        // rect height (2 y-groups)
    tx = (xcd & 3) * rw + (s % rw);
    ty = (xcd >> 2) * rh + (s / rw);
}

// ---------- 4-phase full-acc kernel (proj + score; r7-measured best) ------
// Each phase = FULL acc[8][4] over one K-half slot: 32 MFMA + 12 ds_read.
// vmcnt ledger: every phase stages 1 pair (4 loads) then waits vmcnt(8) ->
// lands the 2-phase-old pair = the slot read by this phase's trailing LD.
// Tail: P1 vmcnt(4), P2 vmcnt(0), P3 none. Prologue: 3 pairs, vmcnt(4).
template<int NB, bool BF16_OUT, bool HAS_BIAS, bool ALLOW_TRANS>
__global__ __launch_bounds__(512, 2) void gemm4ph(
    GemmArgs<NB> args, int M, int N, int K, int ldk, float scale)
{
    __shared__ __align__(16) ushort_t lA[4 * 1024 * 8];     // 64 KB
    __shared__ __align__(16) ushort_t lB[4 * 1024 * 8];     // 64 KB

    const int z = blockIdx.z;
    const ushort_t* __restrict__ A = args.A[z] + args.koff[z];
    const ushort_t* __restrict__ B = args.B[z] + args.koff[z];

    const int tid  = threadIdx.x;
    const int lane = tid & 63;
    const int wave = tid >> 6;
    const int wm   = wave >> 2;
    const int wn   = wave & 3;
    const int quad = lane >> 4;
    const int r16  = lane & 15;

    int tx, ty;
    xcd_swz(tx, ty);
    const int row0 = tx * 256;
    const int col0 = ty * 256;

    floatx4 acc[8][4] = {};

    const ushort_t* pA0; const ushort_t* pA1;
    const ushort_t* pB0; const ushort_t* pB1;
    {
        int c0 = tid,        i0 = c0 >> 6, q0 = (c0 >> 4) & 3, r0 = c0 & 15;
        int c1 = 512 + tid,  i1 = c1 >> 6, q1 = (c1 >> 4) & 3, r1 = c1 & 15;
        pA0 = A + (size_t)(row0 + i0 * 16 + r0) * ldk + q0 * 8;
        pA1 = A + (size_t)(row0 + i1 * 16 + r1) * ldk + q1 * 8;
        pB0 = B + (size_t)(col0 + i0 * 16 + r0) * ldk + q0 * 8;
        pB1 = B + (size_t)(col0 + i1 * 16 + r1) * ldk + q1 * 8;
    }

    auto STAB = [&](int slot) {        // one stage-pair: A + B of one slot
        gload_lds16(pA0, &lA[(slot * 1024 + tid) * 8]);
        gload_lds16(pA1, &lA[(slot * 1024 + 512 + tid) * 8]);
        pA0 += 32; pA1 += 32;
        gload_lds16(pB0, &lB[(slot * 1024 + tid) * 8]);
        gload_lds16(pB1, &lB[(slot * 1024 + 512 + tid) * 8]);
        pB0 += 32; pB1 += 32;
    };

    const int aoff = wm * 512 + lane;
    const int boff = wn * 256 + lane;

    bf16x8 afA[8], bfA[4], afB[8], bfB[4];

    auto LD12 = [&](bf16x8 (&af)[8], bf16x8 (&bf)[4], int slot) {
        #pragma unroll
        for (int j = 0; j < 4; j++)
            bf[j] = *(const bf16x8*)&lB[(slot * 1024 + boff + j * 64) * 8];
        #pragma unroll
        for (int i = 0; i < 8; i++)
            af[i] = *(const bf16x8*)&lA[(slot * 1024 + aoff + i * 64) * 8];
    };

    auto MM32 = [&](bf16x8 (&af)[8], bf16x8 (&bf)[4]) {
        __builtin_amdgcn_s_setprio(1);
        #pragma unroll
        for (int i = 0; i < 8; i++) {
            #pragma unroll
            for (int j = 0; j < 4; j++)
                acc[i][j] = __builtin_amdgcn_mfma_f32_16x16x32_bf16(
                    af[i], bf[j], acc[i][j], 0, 0, 0);
        }
        __builtin_amdgcn_s_setprio(0);
    };

#define BAR() __builtin_amdgcn_s_barrier()
#define VMW8() asm volatile("s_waitcnt vmcnt(8)" ::: "memory")
#define VMW4() asm volatile("s_waitcnt vmcnt(4)" ::: "memory")
#define VMW0() asm volatile("s_waitcnt vmcnt(0)" ::: "memory")

    const int T = K / 64;
    const int NIT = T / 2;

    STAB(0); STAB(1); STAB(2);
    VMW4();
    BAR();
    LD12(afA, bfA, 0);

    for (int it = 0; it < NIT; it++) {
        const bool nl = (it + 1 < NIT);
        STAB(3);
        VMW8();
        BAR();
        MM32(afA, bfA);
        LD12(afB, bfB, 1);
        BAR();
        if (nl) { STAB(0); VMW8(); } else { VMW4(); }
        BAR();
        MM32(afB, bfB);
        LD12(afA, bfA, 2);
        BAR();
        if (nl) { STAB(1); VMW8(); } else { VMW0(); }
        BAR();
        MM32(afA, bfA);
        LD12(afB, bfB, 3);
        BAR();
        if (nl) { STAB(2); VMW8(); }
        BAR();
        MM32(afB, bfB);
        LD12(afA, bfA, 0);       // tail: stale, unused
        BAR();
    }

#undef BAR
#undef VMW8
#undef VMW4
#undef VMW0

    // epilogue
    float bv[4];
    if (HAS_BIAS) {
        #pragma unroll
        for (int j = 0; j < 4; j++)
            bv[j] = args.bias[z][col0 + (wn * 4 + j) * 16 + r16];
    }

    void* C = args.C[z];
    const bool do_trans = ALLOW_TRANS && args.trans[z];

    #pragma unroll
    for (int i = 0; i < 8; i++) {
        const int m_base = row0 + (wm * 8 + i) * 16 + quad * 4;
        #pragma unroll
        for (int j = 0; j < 4; j++) {
            const int n = col0 + (wn * 4 + j) * 16 + r16;
            if (ALLOW_TRANS && do_trans) {
                ushort4 o;
                float v0 = acc[i][j][0] * scale; if (HAS_BIAS) v0 += bv[j];
                float v1 = acc[i][j][1] * scale; if (HAS_BIAS) v1 += bv[j];
                float v2 = acc[i][j][2] * scale; if (HAS_BIAS) v2 += bv[j];
                float v3 = acc[i][j][3] * scale; if (HAS_BIAS) v3 += bv[j];
                o.x = f2bf(v0); o.y = f2bf(v1); o.z = f2bf(v2); o.w = f2bf(v3);
                *(ushort4*)((ushort_t*)C + (size_t)n * M + m_base) = o;
            } else {
                #pragma unroll
                for (int r = 0; r < 4; r++) {
                    float v = acc[i][j][r] * scale;
                    if (HAS_BIAS) v += bv[j];
                    size_t off = (size_t)(m_base + r) * N + n;
                    if (BF16_OUT) ((ushort_t*)C)[off] = f2bf(v);
                    else          ((float*)C)[off] = v;
                }
            }
        }
    }
}

// ---------- 8-phase kernel (PV; r5-measured best: 93.7 vs 111.5 us) -------
// Phases of 16 MFMA; fragment double-buffer; per-EVEN-phase vmcnt(8)
// (CB==2) leaves 4 youngest half-slot stages in flight. ATOMIC_OUT epilogue
// for split-K: both splits atomicAdd into pre-zeroed fp32 C (distinct
// addresses -> no contention; float add commutative -> deterministic).
template<int NB, int MJ, bool BF16_OUT, bool HAS_BIAS, bool ALLOW_TRANS,
         bool ATOMIC_OUT>
__global__ __launch_bounds__(512, 2) void gemm8ph(
    GemmArgs<NB> args, int M, int N, int K, int ldk, float scale)
{
    constexpr int BN = MJ * 64;
    constexpr int CB = MJ / 2;
    constexpr int BCH = BN * 4;

    __shared__ __align__(16) ushort_t lA[4 * 1024 * 8];     // 64 KB
    __shared__ __align__(16) ushort_t lB[4 * BN * 32];

    const int z = blockIdx.z;
    const ushort_t* __restrict__ A = args.A[z] + args.koff[z];
    const ushort_t* __restrict__ B = args.B[z] + args.koff[z];

    const int tid  = threadIdx.x;
    const int lane = tid & 63;
    const int wave = tid >> 6;
    const int wm   = wave >> 2;
    const int wn   = wave & 3;
    const int quad = lane >> 4;
    const int r16  = lane & 15;

    int tx, ty;
    xcd_swz(tx, ty);
    const int row0 = tx * 256;
    const int col0 = ty * BN;

    floatx4 acc[8][MJ] = {};

    const ushort_t* pA0; const ushort_t* pA1;
    const ushort_t* pB[CB];
    {
        int c0 = tid,        i0 = c0 >> 6, q0 = (c0 >> 4) & 3, r0 = c0 & 15;
        int c1 = 512 + tid,  i1 = c1 >> 6, q1 = (c1 >> 4) & 3, r1 = c1 & 15;
        pA0 = A + (size_t)(row0 + i0 * 16 + r0) * ldk + q0 * 8;
        pA1 = A + (size_t)(row0 + i1 * 16 + r1) * ldk + q1 * 8;
        #pragma unroll
        for (int c = 0; c < CB; c++) {
            int cc = c * 512 + tid, ii = cc >> 6, qq = (cc >> 4) & 3, rr = cc & 15;
            pB[c] = B + (size_t)(col0 + ii * 16 + rr) * ldk + qq * 8;
        }
    }

    auto STA = [&](int slot) {
        gload_lds16(pA0, &lA[(slot * 1024 + tid) * 8]);
        gload_lds16(pA1, &lA[(slot * 1024 + 512 + tid) * 8]);
        pA0 += 32; pA1 += 32;
    };
    auto STB = [&](int slot) {
        #pragma unroll
        for (int c = 0; c < CB; c++) {
            gload_lds16(pB[c], &lB[(slot * BCH + c * 512 + tid) * 8]);
            pB[c] += 32;
        }
    };

    const int aoff = wm * 512 + lane;
    const int boff = wn * MJ * 64 + lane;

    bf16x8 af_a[4], bfr_a[MJ], af_b[4], bfr_b[MJ];

    auto LD = [&](bf16x8 (&af)[4], bf16x8 (&bfr)[MJ], int slot, int f0) {
        #pragma unroll
        for (int j = 0; j < MJ; j++)
            bfr[j] = *(const bf16x8*)&lB[(slot * BCH + boff + j * 64) * 8];
        #pragma unroll
        for (int i2 = 0; i2 < 4; i2++)
            af[i2] = *(const bf16x8*)&lA[(slot * 1024 + aoff + (f0 + i2) * 64) * 8];
    };

#define MM(AF, BF, F0) do { \
    __builtin_amdgcn_s_setprio(1); \
    _Pragma("unroll") \
    for (int i2 = 0; i2 < 4; i2++) { \
        _Pragma("unroll") \
        for (int j = 0; j < MJ; j++) \
            acc[(F0) + i2][j] = __builtin_amdgcn_mfma_f32_16x16x32_bf16( \
                AF[i2], BF[j], acc[(F0) + i2][j], 0, 0, 0); \
    } \
    __builtin_amdgcn_s_setprio(0); } while (0)

#define BAR() __builtin_amdgcn_s_barrier()
#define VMWS() do { \
    if constexpr (CB == 2) asm volatile("s_waitcnt vmcnt(8)" ::: "memory"); \
    else                   asm volatile("s_waitcnt vmcnt(6)" ::: "memory"); } while (0)
#define VMWP() do { \
    if constexpr (CB == 2) asm volatile("s_waitcnt vmcnt(4)" ::: "memory"); \
    else                   asm volatile("s_waitcnt vmcnt(3)" ::: "memory"); } while (0)
#define VMW0() asm volatile("s_waitcnt vmcnt(0)" ::: "memory")

    const int T = K / 64;
    const int NIT = T / 2;

    STA(0); STB(0); STA(1); STB(1); STA(2); STB(2);
    VMWP();
    BAR();
    LD(af_a, bfr_a, 0, 0);

    for (int it = 0; it < NIT; it++) {
        const bool nl = (it + 1 < NIT);
        STA(3);
        BAR();
        MM(af_a, bfr_a, 0);
        LD(af_b, bfr_b, 0, 4);
        BAR();
        STB(3);
        VMWS();
        BAR();
        MM(af_b, bfr_b, 4);
        LD(af_a, bfr_a, 1, 0);
        BAR();
        if (nl) STA(0);
        BAR();
        MM(af_a, bfr_a, 0);
        LD(af_b, bfr_b, 1, 4);
        BAR();
        if (nl) STB(0);
        if (nl) { VMWS(); } else { VMW0(); }
        BAR();
        MM(af_b, bfr_b, 4);
        LD(af_a, bfr_a, 2, 0);
        BAR();
        if (nl) STA(1);
        BAR();
        MM(af_a, bfr_a, 0);
        LD(af_b, bfr_b, 2, 4);
        BAR();
        if (nl) STB(1);
        if (nl) VMWS();
        BAR();
        MM(af_b, bfr_b, 4);
        LD(af_a, bfr_a, 3, 0);
        BAR();
        if (nl) STA(2);
        BAR();
        MM(af_a, bfr_a, 0);
        LD(af_b, bfr_b, 3, 4);
        BAR();
        if (nl) STB(2);
        if (nl) VMWS();
        BAR();
        MM(af_b, bfr_b, 4);
        LD(af_a, bfr_a, 0, 0);   // tail: stale, unused
        BAR();
    }

#undef MM
#undef BAR
#undef VMWS
#undef VMWP
#undef VMW0

    // epilogue
    float bv[MJ];
    if (HAS_BIAS) {
        #pragma unroll
        for (int j = 0; j < MJ; j++)
            bv[j] = args.bias[z][col0 + (wn * MJ + j) * 16 + r16];
    }

    void* C = args.C[z];
    const bool do_trans = ALLOW_TRANS && args.trans[z];

    #pragma unroll
    for (int i = 0; i < 8; i++) {
        const int m_base = row0 + (wm * 8 + i) * 16 + quad * 4;
        #pragma unroll
        for (int j = 0; j < MJ; j++) {
            const int n = col0 + (wn * MJ + j) * 16 + r16;
            if (ALLOW_TRANS && do_trans) {
                ushort4 o;
                float v0 = acc[i][j][0] * scale; if (HAS_BIAS) v0 += bv[j];
                float v1 = acc[i][j][1] * scale; if (HAS_BIAS) v1 += bv[j];
                float v2 = acc[i][j][2] * scale; if (HAS_BIAS) v2 += bv[j];
                float v3 = acc[i][j][3] * scale; if (HAS_BIAS) v3 += bv[j];
                o.x = f2bf(v0); o.y = f2bf(v1); o.z = f2bf(v2); o.w = f2bf(v3);
                *(ushort4*)((ushort_t*)C + (size_t)n * M + m_base) = o;
            } else {
                #pragma unroll
                for (int r = 0; r < 4; r++) {
                    float v = acc[i][j][r] * scale;
                    if (HAS_BIAS) v += bv[j];
                    size_t off = (size_t)(m_base + r) * N + n;
                    if (ATOMIC_OUT)      atomicAdd((float*)C + off, v);
                    else if (BF16_OUT)   ((ushort_t*)C)[off] = f2bf(v);
                    else                 ((float*)C)[off] = v;
                }
            }
        }
    }
}

// ---------- row softmax, in-place: S[row,0..4095] bf16, fp32 math ----------
struct SmArgs { ushort_t* S[2]; };

__global__ __launch_bounds__(256) void softmax_kernel(SmArgs a) {
    const int N = 4096;
    ushort_t* S = a.S[blockIdx.y];
    const int row = blockIdx.x;
    const int tid = threadIdx.x;
    const int lane = tid & 63;
    const int wave = tid >> 6;

    bf16x8* ptr = (bf16x8*)(S + (size_t)row * N);
    bf16x8 c0 = ptr[2 * tid];
    bf16x8 c1 = ptr[2 * tid + 1];

    float x[16];
    #pragma unroll
    for (int k = 0; k < 8; k++) {
        x[k]     = bf2f((ushort_t)c0[k]);
        x[8 + k] = bf2f((ushort_t)c1[k]);
    }

    float m = -3.4e38f;
    #pragma unroll
    for (int k = 0; k < 16; k++) m = fmaxf(m, x[k]);
    #pragma unroll
    for (int off = 32; off > 0; off >>= 1) m = fmaxf(m, __shfl_xor(m, off));

    __shared__ float redmax[4], redsum[4];
    if (lane == 0) redmax[wave] = m;
    __syncthreads();
    m = fmaxf(fmaxf(redmax[0], redmax[1]), fmaxf(redmax[2], redmax[3]));

    float s = 0.f;
    #pragma unroll
    for (int k = 0; k < 16; k++) { x[k] = __expf(x[k] - m); s += x[k]; }
    #pragma unroll
    for (int off = 32; off > 0; off >>= 1) s += __shfl_xor(s, off);
    if (lane == 0) redsum[wave] = s;
    __syncthreads();
    s = redsum[0] + redsum[1] + redsum[2] + redsum[3];
    const float inv = 1.0f / s;

    bf16x8 o0, o1;
    #pragma unroll
    for (int k = 0; k < 8; k++) {
        o0[k] = (short)f2bf(x[k] * inv);
        o1[k] = (short)f2bf(x[8 + k] * inv);
    }
    ptr[2 * tid]     = o0;
    ptr[2 * tid + 1] = o1;
}

// ---------- launch ----------
extern "C" void kernel_launch(void* const* d_in, const int* in_sizes, int n_in,
                              void* d_out, int out_size, void* d_ws, size_t ws_size,
                              hipStream_t stream) {
    (void)in_sizes; (void)n_in; (void)out_size;
    const int NC = 4096, NP = 4096, D = 1024;

    char* ws = (char*)d_ws;
    size_t off = 0;
    auto alloc = [&](size_t b) { size_t o = off; off += (b + 255) & ~(size_t)255; return o; };

    ushort_t* xb[6];
    for (int i = 0; i < 6; i++) xb[i] = (ushort_t*)(ws + alloc((size_t)NC * D * 2));
    ushort_t* wb[6];
    for (int i = 0; i < 6; i++) wb[i] = (ushort_t*)(ws + alloc((size_t)D * D * 2));
    ushort_t* qc  = (ushort_t*)(ws + alloc((size_t)NC * D * 2));
    ushort_t* kc  = (ushort_t*)(ws + alloc((size_t)NC * D * 2));
    ushort_t* qp  = (ushort_t*)(ws + alloc((size_t)NP * D * 2));
    ushort_t* kp  = (ushort_t*)(ws + alloc((size_t)NP * D * 2));
    ushort_t* vcT = (ushort_t*)(ws + alloc((size_t)NC * D * 2)); // [D][NC]
    ushort_t* vpT = (ushort_t*)(ws + alloc((size_t)NP * D * 2)); // [D][NP]
    ushort_t* Sb1 = (ushort_t*)(ws + alloc((size_t)4096 * 4096 * 2));
    ushort_t* Sb2 = (ushort_t*)(ws + alloc((size_t)4096 * 4096 * 2));

    if (ws_size < off) return;

    // convert inputs + weights to bf16 (one dispatch)
    CvtArgs ca;
    for (int i = 0; i < 6; i++) {
        ca.src[i] = (const float*)d_in[i];
        ca.dst[i] = xb[i];
        ca.n4[i] = NC * D / 4;
    }
    const int widx[6] = {6, 8, 10, 12, 14, 16};
    for (int i = 0; i < 6; i++) {
        ca.src[6 + i] = (const float*)d_in[widx[i]];
        ca.dst[6 + i] = wb[i];
        ca.n4[6 + i] = D * D / 4;
    }
    cvt_kernel<<<dim3(256, 12), 256, 0, stream>>>(ca);

    // zero d_out for the PV atomic-add epilogue (graph-capturable memset)
    hipMemsetAsync(d_out, 0, (size_t)2 * NC * D * 4, stream);

    const dim3 blk(512);
    const float inv_scale = 1.0f / 32.0f; // 1/sqrt(D_OUT)

    float* out_c = (float*)d_out;                       // comp_fused [NC, D]
    float* out_p = (float*)d_out + (size_t)NC * D;      // prot_fused [NP, D]

    // --- 6 projections: 256x256 4-phase, K=1024; grid (16,4,6) ---
    {
        GemmArgs<6> ga;
        ushort_t* outs[6] = {qc, kc, vcT, qp, kp, vpT};
        const int bidx[6] = {7, 9, 11, 13, 15, 17};
        for (int i = 0; i < 6; i++) {
            ga.A[i] = xb[i];
            ga.B[i] = wb[i];
            ga.bias[i] = (const float*)d_in[bidx[i]];
            ga.C[i] = outs[i];
            ga.trans[i] = (i == 2 || i == 5);   // v projections -> transposed
            ga.koff[i] = 0;
        }
        gemm4ph<6, true, true, true>
            <<<dim3(NC / 256, D / 256, 6), blk, 0, stream>>>(ga, NC, D, D, D, 1.0f);
    }

    // --- 2 score GEMMs: 256x256 4-phase, K=1024; grid (16,16,2) ---
    {
        GemmArgs<2> ga;
        ga.A[0] = qc; ga.B[0] = kp; ga.C[0] = Sb1;
        ga.A[1] = qp; ga.B[1] = kc; ga.C[1] = Sb2;
        ga.bias[0] = ga.bias[1] = nullptr;
        ga.trans[0] = ga.trans[1] = 0;
        ga.koff[0] = ga.koff[1] = 0;
        gemm4ph<2, true, false, false>
            <<<dim3(4096 / 256, 4096 / 256, 2), blk, 0, stream>>>(
                ga, 4096, 4096, D, D, inv_scale);
    }

    // --- 2 softmaxes, one dispatch, in-place ---
    {
        SmArgs sa; sa.S[0] = Sb1; sa.S[1] = Sb2;
        softmax_kernel<<<dim3(4096, 2), dim3(256), 0, stream>>>(sa);
    }

    // --- PV: split-K=2, 8-phase, atomicAdd into zeroed d_out;
    //     grid (16,4,4) = 256 blocks = 1/CU. No partial buffer, no add pass.
    {
        GemmArgs<4> ga;
        ga.A[0] = Sb1; ga.B[0] = vpT; ga.C[0] = out_c; ga.koff[0] = 0;
        ga.A[1] = Sb1; ga.B[1] = vpT; ga.C[1] = out_c; ga.koff[1] = 2048;
        ga.A[2] = Sb2; ga.B[2] = vcT; ga.C[2] = out_p; ga.koff[2] = 0;
        ga.A[3] = Sb2; ga.B[3] = vcT; ga.C[3] = out_p; ga.koff[3] = 2048;
        for (int i = 0; i < 4; i++) { ga.bias[i] = nullptr; ga.trans[i] = 0; }
        gemm8ph<4, 4, false, false, false, true>
            <<<dim3(4096 / 256, D / 256, 4), blk, 0, stream>>>(
                ga, 4096, D, 2048, 4096, 1.0f);
    }
}

// Round 10
// 459.188 us; speedup vs baseline: 1.0680x; 1.0680x over previous
//
#include <hip/hip_runtime.h>

typedef unsigned short ushort_t;
typedef short bf16x8 __attribute__((ext_vector_type(8)));
typedef float floatx4 __attribute__((ext_vector_type(4)));

// ---------- bf16 helpers (bit-level, RNE) ----------
__device__ __forceinline__ float bf2f(ushort_t u) {
    return __uint_as_float(((unsigned)u) << 16);
}
__device__ __forceinline__ ushort_t f2bf(float f) {
    unsigned u = __float_as_uint(f);
    unsigned rnd = 0x7fffu + ((u >> 16) & 1u);
    return (ushort_t)((u + rnd) >> 16);
}

// async global->LDS, 16B per lane; LDS dest = wave-uniform base + lane*16.
__device__ __forceinline__ void gload_lds16(const void* g, void* l) {
    __builtin_amdgcn_global_load_lds(
        (const __attribute__((address_space(1))) unsigned int*)g,
        (__attribute__((address_space(3))) unsigned int*)l,
        16, 0, 0);
}

// ---------- fp32 -> bf16 batch convert ----------
struct CvtArgs {
    const float* src[12];
    ushort_t* dst[12];
    int n4[12];
};

__global__ __launch_bounds__(256) void cvt_kernel(CvtArgs a) {
    int t = blockIdx.y;
    int n4 = a.n4[t];
    const float4* s = (const float4*)a.src[t];
    ushort_t* d = a.dst[t];
    int stride = gridDim.x * blockDim.x;
    for (int i = blockIdx.x * blockDim.x + threadIdx.x; i < n4; i += stride) {
        float4 v = s[i];
        ushort4 o;
        o.x = f2bf(v.x); o.y = f2bf(v.y); o.z = f2bf(v.z); o.w = f2bf(v.w);
        ((ushort4*)d)[i] = o;
    }
}

// ---------- fp32 elementwise add: out += part ----------
__global__ __launch_bounds__(256) void add_kernel(float* out, const float* part, int n4) {
    int stride = gridDim.x * blockDim.x;
    for (int i = blockIdx.x * blockDim.x + threadIdx.x; i < n4; i += stride) {
        float4 o = ((float4*)out)[i];
        float4 p = ((const float4*)part)[i];
        o.x += p.x; o.y += p.y; o.z += p.z; o.w += p.w;
        ((float4*)out)[i] = o;
    }
}

// ============================================================================
// Measured-best schedule per dispatch (r5/r7/r8 A-B results):
//   proj+score (K=1024, ldk=1024): 4-phase full-acc  (r7: beat 8ph by ~28us)
//   PV (split-K=2, K=2048, ldk=4096): 8-phase + partial+add (r5: 93.7us vs
//     4ph 111.5us (r7) vs 8ph-atomic 124.7us (r8 -- atomic RMW added 40MB
//     HBM traffic: WRITE 49->65.5MB, FETCH 74->98MB))
// Common: 256x256 tile, 8 waves (2Mx4N), chunk-linear LDS slots
// (chunk c = i*64+q*16+r holds X[i*16+r][q*8..+7]; staging dest and
// fragment ds_reads lane-linear, 0 bank conflicts), gload_lds16 staging,
// counted vmcnt (never 0 in steady state), raw s_barrier, setprio around
// MFMA clusters, XCD 2D-rect swizzle, split-K (koff/ldk).
// ============================================================================
template<int NB> struct GemmArgs {
    const ushort_t* A[NB];
    const ushort_t* B[NB];
    const float* bias[NB];
    void* C[NB];
    int trans[NB];
    int koff[NB];
};

__device__ __forceinline__ void xcd_swz(int& tx, int& ty) {
    const int gx = gridDim.x, gy = gridDim.y;
    const int l = blockIdx.x + blockIdx.y * gx;
    const int xcd = l & 7, s = l >> 3;
    const int rw = gx >> 2;        // rect width  (4 x-groups)
    const int rh = gy >> 1;        // rect height (2 y-groups)
    tx = (xcd & 3) * rw + (s % rw);
    ty = (xcd >> 2) * rh + (s / rw);
}

// ---------- 4-phase full-acc kernel (proj + score) ------------------------
// Each phase = FULL acc[8][4] over one K-half slot: 32 MFMA + 12 ds_read.
// vmcnt ledger: every phase stages 1 pair (4 loads) then waits vmcnt(8) ->
// lands the 2-phase-old pair = the slot read by this phase's trailing LD.
// Tail: P1 vmcnt(4), P2 vmcnt(0), P3 none. Prologue: 3 pairs, vmcnt(4).
template<int NB, bool BF16_OUT, bool HAS_BIAS, bool ALLOW_TRANS>
__global__ __launch_bounds__(512, 2) void gemm4ph(
    GemmArgs<NB> args, int M, int N, int K, int ldk, float scale)
{
    __shared__ __align__(16) ushort_t lA[4 * 1024 * 8];     // 64 KB
    __shared__ __align__(16) ushort_t lB[4 * 1024 * 8];     // 64 KB

    const int z = blockIdx.z;
    const ushort_t* __restrict__ A = args.A[z] + args.koff[z];
    const ushort_t* __restrict__ B = args.B[z] + args.koff[z];

    const int tid  = threadIdx.x;
    const int lane = tid & 63;
    const int wave = tid >> 6;
    const int wm   = wave >> 2;
    const int wn   = wave & 3;
    const int quad = lane >> 4;
    const int r16  = lane & 15;

    int tx, ty;
    xcd_swz(tx, ty);
    const int row0 = tx * 256;
    const int col0 = ty * 256;

    floatx4 acc[8][4] = {};

    const ushort_t* pA0; const ushort_t* pA1;
    const ushort_t* pB0; const ushort_t* pB1;
    {
        int c0 = tid,        i0 = c0 >> 6, q0 = (c0 >> 4) & 3, r0 = c0 & 15;
        int c1 = 512 + tid,  i1 = c1 >> 6, q1 = (c1 >> 4) & 3, r1 = c1 & 15;
        pA0 = A + (size_t)(row0 + i0 * 16 + r0) * ldk + q0 * 8;
        pA1 = A + (size_t)(row0 + i1 * 16 + r1) * ldk + q1 * 8;
        pB0 = B + (size_t)(col0 + i0 * 16 + r0) * ldk + q0 * 8;
        pB1 = B + (size_t)(col0 + i1 * 16 + r1) * ldk + q1 * 8;
    }

    auto STAB = [&](int slot) {        // one stage-pair: A + B of one slot
        gload_lds16(pA0, &lA[(slot * 1024 + tid) * 8]);
        gload_lds16(pA1, &lA[(slot * 1024 + 512 + tid) * 8]);
        pA0 += 32; pA1 += 32;
        gload_lds16(pB0, &lB[(slot * 1024 + tid) * 8]);
        gload_lds16(pB1, &lB[(slot * 1024 + 512 + tid) * 8]);
        pB0 += 32; pB1 += 32;
    };

    const int aoff = wm * 512 + lane;
    const int boff = wn * 256 + lane;

    bf16x8 afA[8], bfA[4], afB[8], bfB[4];

    auto LD12 = [&](bf16x8 (&af)[8], bf16x8 (&bf)[4], int slot) {
        #pragma unroll
        for (int j = 0; j < 4; j++)
            bf[j] = *(const bf16x8*)&lB[(slot * 1024 + boff + j * 64) * 8];
        #pragma unroll
        for (int i = 0; i < 8; i++)
            af[i] = *(const bf16x8*)&lA[(slot * 1024 + aoff + i * 64) * 8];
    };

    auto MM32 = [&](bf16x8 (&af)[8], bf16x8 (&bf)[4]) {
        __builtin_amdgcn_s_setprio(1);
        #pragma unroll
        for (int i = 0; i < 8; i++) {
            #pragma unroll
            for (int j = 0; j < 4; j++)
                acc[i][j] = __builtin_amdgcn_mfma_f32_16x16x32_bf16(
                    af[i], bf[j], acc[i][j], 0, 0, 0);
        }
        __builtin_amdgcn_s_setprio(0);
    };

#define BAR() __builtin_amdgcn_s_barrier()
#define VMW8() asm volatile("s_waitcnt vmcnt(8)" ::: "memory")
#define VMW4() asm volatile("s_waitcnt vmcnt(4)" ::: "memory")
#define VMW0() asm volatile("s_waitcnt vmcnt(0)" ::: "memory")

    const int T = K / 64;
    const int NIT = T / 2;

    STAB(0); STAB(1); STAB(2);
    VMW4();
    BAR();
    LD12(afA, bfA, 0);

    for (int it = 0; it < NIT; it++) {
        const bool nl = (it + 1 < NIT);
        STAB(3);
        VMW8();
        BAR();
        MM32(afA, bfA);
        LD12(afB, bfB, 1);
        BAR();
        if (nl) { STAB(0); VMW8(); } else { VMW4(); }
        BAR();
        MM32(afB, bfB);
        LD12(afA, bfA, 2);
        BAR();
        if (nl) { STAB(1); VMW8(); } else { VMW0(); }
        BAR();
        MM32(afA, bfA);
        LD12(afB, bfB, 3);
        BAR();
        if (nl) { STAB(2); VMW8(); }
        BAR();
        MM32(afB, bfB);
        LD12(afA, bfA, 0);       // tail: stale, unused
        BAR();
    }

#undef BAR
#undef VMW8
#undef VMW4
#undef VMW0

    // epilogue
    float bv[4];
    if (HAS_BIAS) {
        #pragma unroll
        for (int j = 0; j < 4; j++)
            bv[j] = args.bias[z][col0 + (wn * 4 + j) * 16 + r16];
    }

    void* C = args.C[z];
    const bool do_trans = ALLOW_TRANS && args.trans[z];

    #pragma unroll
    for (int i = 0; i < 8; i++) {
        const int m_base = row0 + (wm * 8 + i) * 16 + quad * 4;
        #pragma unroll
        for (int j = 0; j < 4; j++) {
            const int n = col0 + (wn * 4 + j) * 16 + r16;
            if (ALLOW_TRANS && do_trans) {
                ushort4 o;
                float v0 = acc[i][j][0] * scale; if (HAS_BIAS) v0 += bv[j];
                float v1 = acc[i][j][1] * scale; if (HAS_BIAS) v1 += bv[j];
                float v2 = acc[i][j][2] * scale; if (HAS_BIAS) v2 += bv[j];
                float v3 = acc[i][j][3] * scale; if (HAS_BIAS) v3 += bv[j];
                o.x = f2bf(v0); o.y = f2bf(v1); o.z = f2bf(v2); o.w = f2bf(v3);
                *(ushort4*)((ushort_t*)C + (size_t)n * M + m_base) = o;
            } else {
                #pragma unroll
                for (int r = 0; r < 4; r++) {
                    float v = acc[i][j][r] * scale;
                    if (HAS_BIAS) v += bv[j];
                    size_t off = (size_t)(m_base + r) * N + n;
                    if (BF16_OUT) ((ushort_t*)C)[off] = f2bf(v);
                    else          ((float*)C)[off] = v;
                }
            }
        }
    }
}

// ---------- 8-phase kernel (PV; r5-measured best: 93.7us) -----------------
// Phases of 16 MFMA; fragment double-buffer; per-EVEN-phase vmcnt(8)
// (CB==2) leaves 4 youngest half-slot stages in flight. Plain fp32 stores;
// split-K reduction via separate add_kernel (measured cheaper than atomics:
// r8 atomic = +31us from +40MB RMW traffic).
template<int NB, int MJ, bool BF16_OUT, bool HAS_BIAS, bool ALLOW_TRANS>
__global__ __launch_bounds__(512, 2) void gemm8ph(
    GemmArgs<NB> args, int M, int N, int K, int ldk, float scale)
{
    constexpr int BN = MJ * 64;
    constexpr int CB = MJ / 2;
    constexpr int BCH = BN * 4;

    __shared__ __align__(16) ushort_t lA[4 * 1024 * 8];     // 64 KB
    __shared__ __align__(16) ushort_t lB[4 * BN * 32];

    const int z = blockIdx.z;
    const ushort_t* __restrict__ A = args.A[z] + args.koff[z];
    const ushort_t* __restrict__ B = args.B[z] + args.koff[z];

    const int tid  = threadIdx.x;
    const int lane = tid & 63;
    const int wave = tid >> 6;
    const int wm   = wave >> 2;
    const int wn   = wave & 3;
    const int quad = lane >> 4;
    const int r16  = lane & 15;

    int tx, ty;
    xcd_swz(tx, ty);
    const int row0 = tx * 256;
    const int col0 = ty * BN;

    floatx4 acc[8][MJ] = {};

    const ushort_t* pA0; const ushort_t* pA1;
    const ushort_t* pB[CB];
    {
        int c0 = tid,        i0 = c0 >> 6, q0 = (c0 >> 4) & 3, r0 = c0 & 15;
        int c1 = 512 + tid,  i1 = c1 >> 6, q1 = (c1 >> 4) & 3, r1 = c1 & 15;
        pA0 = A + (size_t)(row0 + i0 * 16 + r0) * ldk + q0 * 8;
        pA1 = A + (size_t)(row0 + i1 * 16 + r1) * ldk + q1 * 8;
        #pragma unroll
        for (int c = 0; c < CB; c++) {
            int cc = c * 512 + tid, ii = cc >> 6, qq = (cc >> 4) & 3, rr = cc & 15;
            pB[c] = B + (size_t)(col0 + ii * 16 + rr) * ldk + qq * 8;
        }
    }

    auto STA = [&](int slot) {
        gload_lds16(pA0, &lA[(slot * 1024 + tid) * 8]);
        gload_lds16(pA1, &lA[(slot * 1024 + 512 + tid) * 8]);
        pA0 += 32; pA1 += 32;
    };
    auto STB = [&](int slot) {
        #pragma unroll
        for (int c = 0; c < CB; c++) {
            gload_lds16(pB[c], &lB[(slot * BCH + c * 512 + tid) * 8]);
            pB[c] += 32;
        }
    };

    const int aoff = wm * 512 + lane;
    const int boff = wn * MJ * 64 + lane;

    bf16x8 af_a[4], bfr_a[MJ], af_b[4], bfr_b[MJ];

    auto LD = [&](bf16x8 (&af)[4], bf16x8 (&bfr)[MJ], int slot, int f0) {
        #pragma unroll
        for (int j = 0; j < MJ; j++)
            bfr[j] = *(const bf16x8*)&lB[(slot * BCH + boff + j * 64) * 8];
        #pragma unroll
        for (int i2 = 0; i2 < 4; i2++)
            af[i2] = *(const bf16x8*)&lA[(slot * 1024 + aoff + (f0 + i2) * 64) * 8];
    };

#define MM(AF, BF, F0) do { \
    __builtin_amdgcn_s_setprio(1); \
    _Pragma("unroll") \
    for (int i2 = 0; i2 < 4; i2++) { \
        _Pragma("unroll") \
        for (int j = 0; j < MJ; j++) \
            acc[(F0) + i2][j] = __builtin_amdgcn_mfma_f32_16x16x32_bf16( \
                AF[i2], BF[j], acc[(F0) + i2][j], 0, 0, 0); \
    } \
    __builtin_amdgcn_s_setprio(0); } while (0)

#define BAR() __builtin_amdgcn_s_barrier()
#define VMWS() do { \
    if constexpr (CB == 2) asm volatile("s_waitcnt vmcnt(8)" ::: "memory"); \
    else                   asm volatile("s_waitcnt vmcnt(6)" ::: "memory"); } while (0)
#define VMWP() do { \
    if constexpr (CB == 2) asm volatile("s_waitcnt vmcnt(4)" ::: "memory"); \
    else                   asm volatile("s_waitcnt vmcnt(3)" ::: "memory"); } while (0)
#define VMW0() asm volatile("s_waitcnt vmcnt(0)" ::: "memory")

    const int T = K / 64;
    const int NIT = T / 2;

    STA(0); STB(0); STA(1); STB(1); STA(2); STB(2);
    VMWP();
    BAR();
    LD(af_a, bfr_a, 0, 0);

    for (int it = 0; it < NIT; it++) {
        const bool nl = (it + 1 < NIT);
        STA(3);
        BAR();
        MM(af_a, bfr_a, 0);
        LD(af_b, bfr_b, 0, 4);
        BAR();
        STB(3);
        VMWS();
        BAR();
        MM(af_b, bfr_b, 4);
        LD(af_a, bfr_a, 1, 0);
        BAR();
        if (nl) STA(0);
        BAR();
        MM(af_a, bfr_a, 0);
        LD(af_b, bfr_b, 1, 4);
        BAR();
        if (nl) STB(0);
        if (nl) { VMWS(); } else { VMW0(); }
        BAR();
        MM(af_b, bfr_b, 4);
        LD(af_a, bfr_a, 2, 0);
        BAR();
        if (nl) STA(1);
        BAR();
        MM(af_a, bfr_a, 0);
        LD(af_b, bfr_b, 2, 4);
        BAR();
        if (nl) STB(1);
        if (nl) VMWS();
        BAR();
        MM(af_b, bfr_b, 4);
        LD(af_a, bfr_a, 3, 0);
        BAR();
        if (nl) STA(2);
        BAR();
        MM(af_a, bfr_a, 0);
        LD(af_b, bfr_b, 3, 4);
        BAR();
        if (nl) STB(2);
        if (nl) VMWS();
        BAR();
        MM(af_b, bfr_b, 4);
        LD(af_a, bfr_a, 0, 0);   // tail: stale, unused
        BAR();
    }

#undef MM
#undef BAR
#undef VMWS
#undef VMWP
#undef VMW0

    // epilogue
    float bv[MJ];
    if (HAS_BIAS) {
        #pragma unroll
        for (int j = 0; j < MJ; j++)
            bv[j] = args.bias[z][col0 + (wn * MJ + j) * 16 + r16];
    }

    void* C = args.C[z];
    const bool do_trans = ALLOW_TRANS && args.trans[z];

    #pragma unroll
    for (int i = 0; i < 8; i++) {
        const int m_base = row0 + (wm * 8 + i) * 16 + quad * 4;
        #pragma unroll
        for (int j = 0; j < MJ; j++) {
            const int n = col0 + (wn * MJ + j) * 16 + r16;
            if (ALLOW_TRANS && do_trans) {
                ushort4 o;
                float v0 = acc[i][j][0] * scale; if (HAS_BIAS) v0 += bv[j];
                float v1 = acc[i][j][1] * scale; if (HAS_BIAS) v1 += bv[j];
                float v2 = acc[i][j][2] * scale; if (HAS_BIAS) v2 += bv[j];
                float v3 = acc[i][j][3] * scale; if (HAS_BIAS) v3 += bv[j];
                o.x = f2bf(v0); o.y = f2bf(v1); o.z = f2bf(v2); o.w = f2bf(v3);
                *(ushort4*)((ushort_t*)C + (size_t)n * M + m_base) = o;
            } else {
                #pragma unroll
                for (int r = 0; r < 4; r++) {
                    float v = acc[i][j][r] * scale;
                    if (HAS_BIAS) v += bv[j];
                    size_t off = (size_t)(m_base + r) * N + n;
                    if (BF16_OUT) ((ushort_t*)C)[off] = f2bf(v);
                    else          ((float*)C)[off] = v;
                }
            }
        }
    }
}

// ---------- row softmax, in-place: S[row,0..4095] bf16, fp32 math ----------
struct SmArgs { ushort_t* S[2]; };

__global__ __launch_bounds__(256) void softmax_kernel(SmArgs a) {
    const int N = 4096;
    ushort_t* S = a.S[blockIdx.y];
    const int row = blockIdx.x;
    const int tid = threadIdx.x;
    const int lane = tid & 63;
    const int wave = tid >> 6;

    bf16x8* ptr = (bf16x8*)(S + (size_t)row * N);
    bf16x8 c0 = ptr[2 * tid];
    bf16x8 c1 = ptr[2 * tid + 1];

    float x[16];
    #pragma unroll
    for (int k = 0; k < 8; k++) {
        x[k]     = bf2f((ushort_t)c0[k]);
        x[8 + k] = bf2f((ushort_t)c1[k]);
    }

    float m = -3.4e38f;
    #pragma unroll
    for (int k = 0; k < 16; k++) m = fmaxf(m, x[k]);
    #pragma unroll
    for (int off = 32; off > 0; off >>= 1) m = fmaxf(m, __shfl_xor(m, off));

    __shared__ float redmax[4], redsum[4];
    if (lane == 0) redmax[wave] = m;
    __syncthreads();
    m = fmaxf(fmaxf(redmax[0], redmax[1]), fmaxf(redmax[2], redmax[3]));

    float s = 0.f;
    #pragma unroll
    for (int k = 0; k < 16; k++) { x[k] = __expf(x[k] - m); s += x[k]; }
    #pragma unroll
    for (int off = 32; off > 0; off >>= 1) s += __shfl_xor(s, off);
    if (lane == 0) redsum[wave] = s;
    __syncthreads();
    s = redsum[0] + redsum[1] + redsum[2] + redsum[3];
    const float inv = 1.0f / s;

    bf16x8 o0, o1;
    #pragma unroll
    for (int k = 0; k < 8; k++) {
        o0[k] = (short)f2bf(x[k] * inv);
        o1[k] = (short)f2bf(x[8 + k] * inv);
    }
    ptr[2 * tid]     = o0;
    ptr[2 * tid + 1] = o1;
}

// ---------- launch ----------
extern "C" void kernel_launch(void* const* d_in, const int* in_sizes, int n_in,
                              void* d_out, int out_size, void* d_ws, size_t ws_size,
                              hipStream_t stream) {
    (void)in_sizes; (void)n_in; (void)out_size;
    const int NC = 4096, NP = 4096, D = 1024;

    char* ws = (char*)d_ws;
    size_t off = 0;
    auto alloc = [&](size_t b) { size_t o = off; off += (b + 255) & ~(size_t)255; return o; };

    ushort_t* xb[6];
    for (int i = 0; i < 6; i++) xb[i] = (ushort_t*)(ws + alloc((size_t)NC * D * 2));
    ushort_t* wb[6];
    for (int i = 0; i < 6; i++) wb[i] = (ushort_t*)(ws + alloc((size_t)D * D * 2));
    ushort_t* qc  = (ushort_t*)(ws + alloc((size_t)NC * D * 2));
    ushort_t* kc  = (ushort_t*)(ws + alloc((size_t)NC * D * 2));
    ushort_t* qp  = (ushort_t*)(ws + alloc((size_t)NP * D * 2));
    ushort_t* kp  = (ushort_t*)(ws + alloc((size_t)NP * D * 2));
    ushort_t* vcT = (ushort_t*)(ws + alloc((size_t)NC * D * 2)); // [D][NC]
    ushort_t* vpT = (ushort_t*)(ws + alloc((size_t)NP * D * 2)); // [D][NP]
    ushort_t* Sb1 = (ushort_t*)(ws + alloc((size_t)4096 * 4096 * 2));
    ushort_t* Sb2 = (ushort_t*)(ws + alloc((size_t)4096 * 4096 * 2));

    if (ws_size < off) return;

    // convert inputs + weights to bf16 (one dispatch)
    CvtArgs ca;
    for (int i = 0; i < 6; i++) {
        ca.src[i] = (const float*)d_in[i];
        ca.dst[i] = xb[i];
        ca.n4[i] = NC * D / 4;
    }
    const int widx[6] = {6, 8, 10, 12, 14, 16};
    for (int i = 0; i < 6; i++) {
        ca.src[6 + i] = (const float*)d_in[widx[i]];
        ca.dst[6 + i] = wb[i];
        ca.n4[6 + i] = D * D / 4;
    }
    cvt_kernel<<<dim3(256, 12), 256, 0, stream>>>(ca);

    const dim3 blk(512);
    const float inv_scale = 1.0f / 32.0f; // 1/sqrt(D_OUT)

    float* out_c = (float*)d_out;                       // comp_fused [NC, D]
    float* out_p = (float*)d_out + (size_t)NC * D;      // prot_fused [NP, D]

    // --- 6 projections: 256x256 4-phase, K=1024; grid (16,4,6) ---
    {
        GemmArgs<6> ga;
        ushort_t* outs[6] = {qc, kc, vcT, qp, kp, vpT};
        const int bidx[6] = {7, 9, 11, 13, 15, 17};
        for (int i = 0; i < 6; i++) {
            ga.A[i] = xb[i];
            ga.B[i] = wb[i];
            ga.bias[i] = (const float*)d_in[bidx[i]];
            ga.C[i] = outs[i];
            ga.trans[i] = (i == 2 || i == 5);   // v projections -> transposed
            ga.koff[i] = 0;
        }
        gemm4ph<6, true, true, true>
            <<<dim3(NC / 256, D / 256, 6), blk, 0, stream>>>(ga, NC, D, D, D, 1.0f);
    }

    // --- 2 score GEMMs: 256x256 4-phase, K=1024; grid (16,16,2) ---
    {
        GemmArgs<2> ga;
        ga.A[0] = qc; ga.B[0] = kp; ga.C[0] = Sb1;
        ga.A[1] = qp; ga.B[1] = kc; ga.C[1] = Sb2;
        ga.bias[0] = ga.bias[1] = nullptr;
        ga.trans[0] = ga.trans[1] = 0;
        ga.koff[0] = ga.koff[1] = 0;
        gemm4ph<2, true, false, false>
            <<<dim3(4096 / 256, 4096 / 256, 2), blk, 0, stream>>>(
                ga, 4096, 4096, D, D, inv_scale);
    }

    // --- 2 softmaxes, one dispatch, in-place ---
    {
        SmArgs sa; sa.S[0] = Sb1; sa.S[1] = Sb2;
        softmax_kernel<<<dim3(4096, 2), dim3(256), 0, stream>>>(sa);
    }

    // --- PV: split-K=2, 8-phase, fp32 out; grid (16,4,4) = 256 = 1/CU.
    //     sk=0 partials into the dead qc..kp region (32 MB contiguous);
    //     sk=1 straight to d_out; then d_out += part. (r5-measured best.)
    {
        float* part = (float*)qc;                       // 2 x 4096 x 1024 fp32
        GemmArgs<4> ga;
        ga.A[0] = Sb1; ga.B[0] = vpT; ga.C[0] = part;                  ga.koff[0] = 0;
        ga.A[1] = Sb1; ga.B[1] = vpT; ga.C[1] = out_c;                 ga.koff[1] = 2048;
        ga.A[2] = Sb2; ga.B[2] = vcT; ga.C[2] = part + (size_t)NP * D; ga.koff[2] = 0;
        ga.A[3] = Sb2; ga.B[3] = vcT; ga.C[3] = out_p;                 ga.koff[3] = 2048;
        for (int i = 0; i < 4; i++) { ga.bias[i] = nullptr; ga.trans[i] = 0; }
        gemm8ph<4, 4, false, false, false>
            <<<dim3(4096 / 256, D / 256, 4), blk, 0, stream>>>(
                ga, 4096, D, 2048, 4096, 1.0f);

        add_kernel<<<dim3(2048), dim3(256), 0, stream>>>(
            (float*)d_out, part, 2 * NC * D / 4);
    }
}